// Round 2
// baseline (617.037 us; speedup 1.0000x reference)
//
#include <hip/hip_runtime.h>
#include <hip/hip_bf16.h>
#include <cstdint>
#include <cstddef>

// Problem constants
#define K_DIM   4096          // INF
#define N_DIM   11008         // OUTF
#define M_DIM   4096          // 2*2048
#define GROUPS  32
#define QROWS   512           // INF*4/32

typedef __bf16 bf16x8 __attribute__((ext_vector_type(8)));
typedef float  f32x4  __attribute__((ext_vector_type(4)));

// ---------------------------------------------------------------------------
// async 16B global -> LDS (wave-uniform LDS base + lane*16 semantics)
// ---------------------------------------------------------------------------
__device__ __forceinline__ void async16(const void* g, void* lds) {
    __builtin_amdgcn_global_load_lds(
        (const __attribute__((address_space(1))) uint32_t*)g,
        (__attribute__((address_space(3))) uint32_t*)lds,
        16, 0, 0);
}

#define FENCE() asm volatile("" ::: "memory")
#define BAR()   do { FENCE(); __builtin_amdgcn_s_barrier(); FENCE(); } while (0)

// ---------------------------------------------------------------------------
// Kernel 1: dequantize packed 4-bit weights into B^T bf16 layout (N x K).
// (unchanged — revisit once GEMM no longer dominates)
// ---------------------------------------------------------------------------
#define DQ_NN   64
#define DQ_KK   32
#define DQ_ROW  264   // 256 k-elements + 8 pad (16B) -> 528B row stride
__global__ __launch_bounds__(256) void dequant_kernel(
        const uint32_t* __restrict__ qw,
        const float* __restrict__ scales,
        const float* __restrict__ zeros,
        __bf16* __restrict__ Wt) {
    __shared__ __align__(16) __bf16 T[DQ_NN * DQ_ROW];   // 33,792 B

    const int n0  = blockIdx.x * DQ_NN;
    const int kk0 = blockIdx.y * DQ_KK;
    const int tid = threadIdx.x;

#pragma unroll
    for (int it = 0; it < 8; ++it) {
        const int flat = it * 256 + tid;
        const int kk_l = flat >> 6;          // 0..31
        const int n_l  = flat & 63;          // 0..63
        const int kk   = kk0 + kk_l;
        const int n    = n0 + n_l;
        const uint32_t q = qw[(size_t)kk * N_DIM + n];
        const int g = kk >> 4;               // k-group = (kk*8)/128
        const float s = scales[(size_t)n * GROUPS + g];
        const float z = zeros[(size_t)n * GROUPS + g];
        bf16x8 w;
#pragma unroll
        for (int j = 0; j < 8; ++j) {
            float v = (float)((q >> (4 * j)) & 0xF) * s - z;
            w[j] = (__bf16)v;
        }
        *(bf16x8*)(&T[n_l * DQ_ROW + kk_l * 8]) = w;
    }
    __syncthreads();

#pragma unroll
    for (int it = 0; it < 8; ++it) {
        const int flat = it * 256 + tid;
        const int n_l    = flat >> 5;        // 0..63
        const int kchunk = flat & 31;        // 0..31 (8 elems each)
        bf16x8 v = *(const bf16x8*)(&T[n_l * DQ_ROW + kchunk * 8]);
        *(bf16x8*)(Wt + (size_t)(n0 + n_l) * K_DIM + (size_t)kk0 * 8 + kchunk * 8) = v;
    }
}

// ---------------------------------------------------------------------------
// Kernel 2: x fp32 -> bf16 (RNE), 8 elements per thread (unchanged)
// ---------------------------------------------------------------------------
__global__ __launch_bounds__(256) void xconv_kernel(
        const float* __restrict__ x, __bf16* __restrict__ xb) {
    const size_t i = ((size_t)blockIdx.x * 256 + threadIdx.x) * 8;
    const float4* p = (const float4*)(x + i);
    float4 a = p[0];
    float4 b = p[1];
    bf16x8 o;
    o[0] = (__bf16)a.x; o[1] = (__bf16)a.y; o[2] = (__bf16)a.z; o[3] = (__bf16)a.w;
    o[4] = (__bf16)b.x; o[5] = (__bf16)b.y; o[6] = (__bf16)b.z; o[7] = (__bf16)b.w;
    *(bf16x8*)(xb + i) = o;
}

// ---------------------------------------------------------------------------
// Kernel 3: bf16 GEMM, C = A(M x K) * Bt(N x K)^T + bias, fp32 out.
//
// 256x256 tile, BK=64, 512 threads = 8 waves (2M x 4N), per-wave 128x64
// output = acc[8][4] f32x4.  4-phase-per-K-tile, counted vmcnt, setprio,
// XOR-8 LDS swizzle via pre-swizzled global source (rule 21).
//
// R1 change: ALL 8 staging loads for tile g+1 issue at group g PHASE 0
// (need-order: Aq0,Aq2,Bq0-3 first, Aq1,Aq3 last).  The phase-0 barrier
// already guarantees the target buffer's previous-tile reads finished.
// Waits: p0 vmcnt(2)  -> first-6 of CURRENT tile done (lead 4 phases)
//        p2 vmcnt(8)  -> last-2 of current tile done, next tile's 8 in
//                        flight (lead 6 phases ~1000+ cyc).
// Last group: vmcnt(2) / vmcnt(0) drain, no staging.
// ---------------------------------------------------------------------------
#define BM 256
#define BN 256
#define BK 64
#define NT 43            // N_DIM/256
#define MT 16            // M_DIM/256
#define NWG (NT*MT)      // 688 = 8*86 -> bijective XCD swizzle

// 16-MFMA phase body: 4 A-frag ds_reads, barrier, MFMA cluster.
// b?k? fragment registers are in enclosing kgroup scope (loaded in phase 0).
#define PH_BODY(MF)                                                           \
    do {                                                                      \
        bf16x8 aLk0 = *(const bf16x8*)(ar0 + (MF)*1024);                      \
        bf16x8 aLk1 = *(const bf16x8*)(ar1 + (MF)*1024);                      \
        bf16x8 aHk0 = *(const bf16x8*)(ar0 + ((MF)+1)*1024);                  \
        bf16x8 aHk1 = *(const bf16x8*)(ar1 + ((MF)+1)*1024);                  \
        BAR();                                                                \
        __builtin_amdgcn_s_setprio(1);                                        \
        acc[(MF)  ][0] = __builtin_amdgcn_mfma_f32_16x16x32_bf16(aLk0, b0k0, acc[(MF)  ][0], 0,0,0); \
        acc[(MF)  ][1] = __builtin_amdgcn_mfma_f32_16x16x32_bf16(aLk0, b1k0, acc[(MF)  ][1], 0,0,0); \
        acc[(MF)  ][2] = __builtin_amdgcn_mfma_f32_16x16x32_bf16(aLk0, b2k0, acc[(MF)  ][2], 0,0,0); \
        acc[(MF)  ][3] = __builtin_amdgcn_mfma_f32_16x16x32_bf16(aLk0, b3k0, acc[(MF)  ][3], 0,0,0); \
        acc[(MF)+1][0] = __builtin_amdgcn_mfma_f32_16x16x32_bf16(aHk0, b0k0, acc[(MF)+1][0], 0,0,0); \
        acc[(MF)+1][1] = __builtin_amdgcn_mfma_f32_16x16x32_bf16(aHk0, b1k0, acc[(MF)+1][1], 0,0,0); \
        acc[(MF)+1][2] = __builtin_amdgcn_mfma_f32_16x16x32_bf16(aHk0, b2k0, acc[(MF)+1][2], 0,0,0); \
        acc[(MF)+1][3] = __builtin_amdgcn_mfma_f32_16x16x32_bf16(aHk0, b3k0, acc[(MF)+1][3], 0,0,0); \
        acc[(MF)  ][0] = __builtin_amdgcn_mfma_f32_16x16x32_bf16(aLk1, b0k1, acc[(MF)  ][0], 0,0,0); \
        acc[(MF)  ][1] = __builtin_amdgcn_mfma_f32_16x16x32_bf16(aLk1, b1k1, acc[(MF)  ][1], 0,0,0); \
        acc[(MF)  ][2] = __builtin_amdgcn_mfma_f32_16x16x32_bf16(aLk1, b2k1, acc[(MF)  ][2], 0,0,0); \
        acc[(MF)  ][3] = __builtin_amdgcn_mfma_f32_16x16x32_bf16(aLk1, b3k1, acc[(MF)  ][3], 0,0,0); \
        acc[(MF)+1][0] = __builtin_amdgcn_mfma_f32_16x16x32_bf16(aHk1, b0k1, acc[(MF)+1][0], 0,0,0); \
        acc[(MF)+1][1] = __builtin_amdgcn_mfma_f32_16x16x32_bf16(aHk1, b1k1, acc[(MF)+1][1], 0,0,0); \
        acc[(MF)+1][2] = __builtin_amdgcn_mfma_f32_16x16x32_bf16(aHk1, b2k1, acc[(MF)+1][2], 0,0,0); \
        acc[(MF)+1][3] = __builtin_amdgcn_mfma_f32_16x16x32_bf16(aHk1, b3k1, acc[(MF)+1][3], 0,0,0); \
        __builtin_amdgcn_s_setprio(0);                                        \
    } while (0)

// One K-tile (4 phases). ar0/ar1,br0/br1 = this buffer's per-lane ds_read
// bases (ks0/ks1 swizzled cols). soff = staging buffer offset (elements).
template<bool DO_STAGE>
__device__ __forceinline__ void kgroup(
        const __bf16* __restrict__ ar0, const __bf16* __restrict__ ar1,
        const __bf16* __restrict__ br0, const __bf16* __restrict__ br1,
        const __bf16* (&gsrc)[8], __bf16* lds, const int (&ldst)[8],
        const int soff, f32x4 (&acc)[8][4])
{
    // ---- phase 0 : mf 0,1.  Needs current tile's {Aq0,Aq2,B*} = first 6
    // issued loads -> vmcnt(2) leaves {Aq1,Aq3} in flight.
    asm volatile("s_waitcnt vmcnt(2)" ::: "memory");
    BAR();
    bf16x8 b0k0 = *(const bf16x8*)(br0 + 0*1024);
    bf16x8 b1k0 = *(const bf16x8*)(br0 + 1*1024);
    bf16x8 b2k0 = *(const bf16x8*)(br0 + 2*1024);
    bf16x8 b3k0 = *(const bf16x8*)(br0 + 3*1024);
    bf16x8 b0k1 = *(const bf16x8*)(br1 + 0*1024);
    bf16x8 b1k1 = *(const bf16x8*)(br1 + 1*1024);
    bf16x8 b2k1 = *(const bf16x8*)(br1 + 2*1024);
    bf16x8 b3k1 = *(const bf16x8*)(br1 + 3*1024);
    if constexpr (DO_STAGE) {
        // all 8 staging issues for the NEXT tile, need-order.
#pragma unroll
        for (int j = 0; j < 8; ++j)
            async16(gsrc[j], lds + ldst[j] + soff);
    }
    PH_BODY(0);
    // ---- phase 1 : mf 2,3 (Aq0/Aq2) ----
    BAR();
    PH_BODY(2);
    // ---- phase 2 : mf 4,5 (Aq1/Aq3 = last-2 issued loads of current tile;
    // next tile's 8 may remain in flight) ----
    if constexpr (DO_STAGE) { asm volatile("s_waitcnt vmcnt(8)" ::: "memory"); }
    else                    { asm volatile("s_waitcnt vmcnt(0)" ::: "memory"); }
    BAR();
    PH_BODY(4);
    // ---- phase 3 : mf 6,7 ----
    BAR();
    PH_BODY(6);
    if constexpr (DO_STAGE) {
#pragma unroll
        for (int j = 0; j < 8; ++j) gsrc[j] += BK;
    }
}

__global__ __launch_bounds__(512, 2) void gemm_kernel(
        const __bf16* __restrict__ A,    // M x K row-major (bf16 x)
        const __bf16* __restrict__ Bt,   // N x K row-major (dequant W^T)
        const float* __restrict__ bias,  // N
        float* __restrict__ C) {         // M x N row-major
    __shared__ __align__(16) __bf16 lds[65536];   // 128 KiB

    const int tid  = threadIdx.x;
    const int wave = tid >> 6;
    const int lane = tid & 63;
    const int wm   = wave >> 2;      // 0..1
    const int wn   = wave & 3;       // 0..3
    const int quad = lane >> 4;      // 0..3
    const int l16  = lane & 15;

    // bijective XCD swizzle (688 % 8 == 0), m inner for B-panel L2 reuse
    const int bid = blockIdx.x;
    const int swz = (bid & 7) * (NWG / 8) + (bid >> 3);
    const int n_t = swz >> 4;        // 0..42
    const int m_t = swz & 15;        // 0..15
    const int m0 = m_t << 8;
    const int n0 = n_t << 8;

    f32x4 acc[8][4] = {};

    // ---- staging source (pre-swizzled global addresses, rule 21) ----
    const int srow = tid >> 3;                       // 0..63 row within quarter
    const int scol = ((tid & 7) ^ (srow & 7)) << 3;  // swizzled k-chunk * 8

    // issue order: Aq0, Aq2, Bq0, Bq1, Bq2, Bq3, Aq1, Aq3
    const __bf16* gsrc[8];
    gsrc[0] = A  + (size_t)(m0 +   0 + srow) * K_DIM + scol;
    gsrc[1] = A  + (size_t)(m0 + 128 + srow) * K_DIM + scol;
    gsrc[2] = Bt + (size_t)(n0 +   0 + srow) * K_DIM + scol;
    gsrc[3] = Bt + (size_t)(n0 +  64 + srow) * K_DIM + scol;
    gsrc[4] = Bt + (size_t)(n0 + 128 + srow) * K_DIM + scol;
    gsrc[5] = Bt + (size_t)(n0 + 192 + srow) * K_DIM + scol;
    gsrc[6] = A  + (size_t)(m0 +  64 + srow) * K_DIM + scol;
    gsrc[7] = A  + (size_t)(m0 + 192 + srow) * K_DIM + scol;

    // wave-uniform LDS dest (elements): quarter base + wave*512 (HW adds lane*16B)
    const int wq = wave << 9;
    const int ldst[8] = {
        0*4096 + wq,          2*4096 + wq,
        32768 + 0*4096 + wq,  32768 + 1*4096 + wq,
        32768 + 2*4096 + wq,  32768 + 3*4096 + wq,
        1*4096 + wq,          3*4096 + wq
    };

    // prologue: tile 0 -> buf0 (same issue order as steady state)
#pragma unroll
    for (int j = 0; j < 8; ++j) async16(gsrc[j], lds + ldst[j]);
#pragma unroll
    for (int j = 0; j < 8; ++j) gsrc[j] += BK;

    // ---- compute-side ds_read bases (swizzled cols; row&7 == l16&7) ----
    const int h3  = l16 & 7;
    const int cc0 = (quad ^ h3) << 3;          // ks0 col (elements)
    const int cc1 = ((quad ^ h3) ^ 4) << 3;    // ks1 col = cc0 XOR 32 elems
    const int arow = (wm << 7) + l16;          // + mf*16 via imm offset
    const int brow = (wn << 6) + l16;          // + nf*16 via imm offset

    const __bf16* a00 = lds + arow * 64 + cc0;          // buf0 A ks0
    const __bf16* a01 = lds + arow * 64 + cc1;          // buf0 A ks1
    const __bf16* b00 = lds + 32768 + brow * 64 + cc0;  // buf0 B ks0
    const __bf16* b01 = lds + 32768 + brow * 64 + cc1;  // buf0 B ks1

    // 64 K-tiles: groups alternate buf0/buf1; group g stages tile g+1 at its
    // phase 0 into the buffer vacated at end of group g-1.
#pragma unroll 1
    for (int gg = 0; gg < 31; ++gg) {
        kgroup<true>(a00,         a01,         b00,         b01,
                     gsrc, lds, ldst, 16384, acc);
        kgroup<true>(a00 + 16384, a01 + 16384, b00 + 16384, b01 + 16384,
                     gsrc, lds, ldst, 0,     acc);
    }
    kgroup<true >(a00,         a01,         b00,         b01,
                  gsrc, lds, ldst, 16384, acc);   // g=62 stages tile 63
    kgroup<false>(a00 + 16384, a01 + 16384, b00 + 16384, b01 + 16384,
                  gsrc, lds, ldst, 0,     acc);   // g=63, drain

    // ---- epilogue: C[m][n] = acc + bias[n]; C/D: col=l16, row=quad*4+r ----
#pragma unroll
    for (int nf = 0; nf < 4; ++nf) {
        const int n = n0 + (wn << 6) + (nf << 4) + l16;
        const float bv = bias[n];
#pragma unroll
        for (int mf = 0; mf < 8; ++mf) {
            const int mrow = m0 + (wm << 7) + (mf << 4) + (quad << 2);
            float* cp = C + (size_t)mrow * N_DIM + n;
#pragma unroll
            for (int r = 0; r < 4; ++r)
                cp[(size_t)r * N_DIM] = acc[mf][nf][r] + bv;
        }
    }
}

// ---------------------------------------------------------------------------
extern "C" void kernel_launch(void* const* d_in, const int* in_sizes, int n_in,
                              void* d_out, int out_size, void* d_ws, size_t ws_size,
                              hipStream_t stream) {
    const float*    x      = (const float*)d_in[0];
    const uint32_t* qw     = (const uint32_t*)d_in[1];
    const float*    scales = (const float*)d_in[2];
    const float*    zeros  = (const float*)d_in[3];
    const float*    bias   = (const float*)d_in[4];
    float*          out    = (float*)d_out;

    // workspace layout: Wt (N*K bf16 = 90,177,536 B) | xb (M*K bf16 = 33,554,432 B)
    __bf16* Wt = (__bf16*)d_ws;
    __bf16* xb = (__bf16*)((char*)d_ws + (size_t)N_DIM * K_DIM * sizeof(__bf16));

    dim3 dq_grid(N_DIM / DQ_NN, QROWS / DQ_KK);   // 172 x 16
    dequant_kernel<<<dq_grid, 256, 0, stream>>>(qw, scales, zeros, Wt);
    xconv_kernel<<<(M_DIM * K_DIM) / (256 * 8), 256, 0, stream>>>(x, xb);

    gemm_kernel<<<NWG, 512, 0, stream>>>(xb, Wt, bias, out);
}

// Round 3
// 603.140 us; speedup vs baseline: 1.0230x; 1.0230x over previous
//
#include <hip/hip_runtime.h>
#include <hip/hip_bf16.h>
#include <cstdint>
#include <cstddef>

// Problem constants
#define K_DIM   4096          // INF
#define N_DIM   11008         // OUTF
#define M_DIM   4096          // 2*2048
#define GROUPS  32
#define QROWS   512           // INF*4/32

typedef __bf16 bf16x8 __attribute__((ext_vector_type(8)));
typedef float  f32x4  __attribute__((ext_vector_type(4)));

// ---------------------------------------------------------------------------
// async 16B global -> LDS (wave-uniform LDS base + lane*16 semantics)
// ---------------------------------------------------------------------------
__device__ __forceinline__ void async16(const void* g, void* lds) {
    __builtin_amdgcn_global_load_lds(
        (const __attribute__((address_space(1))) uint32_t*)g,
        (__attribute__((address_space(3))) uint32_t*)lds,
        16, 0, 0);
}

#define FENCE() asm volatile("" ::: "memory")
#define BAR()   do { FENCE(); __builtin_amdgcn_s_barrier(); FENCE(); } while (0)

// ---------------------------------------------------------------------------
// Kernel 1: dequantize packed 4-bit weights into B^T bf16 layout (N x K).
// (unchanged — revisit once GEMM no longer dominates)
// ---------------------------------------------------------------------------
#define DQ_NN   64
#define DQ_KK   32
#define DQ_ROW  264   // 256 k-elements + 8 pad (16B) -> 528B row stride
__global__ __launch_bounds__(256) void dequant_kernel(
        const uint32_t* __restrict__ qw,
        const float* __restrict__ scales,
        const float* __restrict__ zeros,
        __bf16* __restrict__ Wt) {
    __shared__ __align__(16) __bf16 T[DQ_NN * DQ_ROW];   // 33,792 B

    const int n0  = blockIdx.x * DQ_NN;
    const int kk0 = blockIdx.y * DQ_KK;
    const int tid = threadIdx.x;

#pragma unroll
    for (int it = 0; it < 8; ++it) {
        const int flat = it * 256 + tid;
        const int kk_l = flat >> 6;          // 0..31
        const int n_l  = flat & 63;          // 0..63
        const int kk   = kk0 + kk_l;
        const int n    = n0 + n_l;
        const uint32_t q = qw[(size_t)kk * N_DIM + n];
        const int g = kk >> 4;               // k-group = (kk*8)/128
        const float s = scales[(size_t)n * GROUPS + g];
        const float z = zeros[(size_t)n * GROUPS + g];
        bf16x8 w;
#pragma unroll
        for (int j = 0; j < 8; ++j) {
            float v = (float)((q >> (4 * j)) & 0xF) * s - z;
            w[j] = (__bf16)v;
        }
        *(bf16x8*)(&T[n_l * DQ_ROW + kk_l * 8]) = w;
    }
    __syncthreads();

#pragma unroll
    for (int it = 0; it < 8; ++it) {
        const int flat = it * 256 + tid;
        const int n_l    = flat >> 5;        // 0..63
        const int kchunk = flat & 31;        // 0..31 (8 elems each)
        bf16x8 v = *(const bf16x8*)(&T[n_l * DQ_ROW + kchunk * 8]);
        *(bf16x8*)(Wt + (size_t)(n0 + n_l) * K_DIM + (size_t)kk0 * 8 + kchunk * 8) = v;
    }
}

// ---------------------------------------------------------------------------
// Kernel 2: x fp32 -> bf16 (RNE), 8 elements per thread (unchanged)
// ---------------------------------------------------------------------------
__global__ __launch_bounds__(256) void xconv_kernel(
        const float* __restrict__ x, __bf16* __restrict__ xb) {
    const size_t i = ((size_t)blockIdx.x * 256 + threadIdx.x) * 8;
    const float4* p = (const float4*)(x + i);
    float4 a = p[0];
    float4 b = p[1];
    bf16x8 o;
    o[0] = (__bf16)a.x; o[1] = (__bf16)a.y; o[2] = (__bf16)a.z; o[3] = (__bf16)a.w;
    o[4] = (__bf16)b.x; o[5] = (__bf16)b.y; o[6] = (__bf16)b.z; o[7] = (__bf16)b.w;
    *(bf16x8*)(xb + i) = o;
}

// ---------------------------------------------------------------------------
// Kernel 3: bf16 GEMM, C = A(M x K) * Bt(N x K)^T + bias, fp32 out.
//
// 256x256 tile, BK=64, 512 threads = 8 waves (2M x 4N), per-wave 128x64
// output = acc[8][4] f32x4.  Counted vmcnt, setprio, XOR-8 LDS swizzle via
// pre-swizzled global source (rule 21).  Staging spread 2-per-phase (R0;
// R1's 8-at-p0 burst regressed from LDS port contention).
//
// R2 change: ks-major phase decomposition to balance LDS reads {8,4,8,4}
// (was {12,4,4,4} -- the phase-0 96-read CU burst stalled every wave's
// lgkmcnt(0) past the 620-cyc MFMA cluster).
//   p0: ks0 x mf0-3 (4A + 4B reads)   p1: ks0 x mf4-7 (4A)
//   p2: ks1 x mf0-3 (4A + 4B)         p3: ks1 x mf4-7 (4A)
// A quarters: wm=0 -> mf0-3 in Aq0, mf4-7 in Aq1; wm=1 -> Aq2/Aq3.
// B quarter: wave wn reads only Bq[wn] (both k-halves).
// Need-order: {Aq0,Aq2,B*} by p0 -> vmcnt(2);  {Aq1,Aq3} by p1 -> vmcnt(2)
// (outstanding there = cur{Aq1,Aq3} + next{Aq0,Aq2}).
// Staging pairs: p0: Aq0,Aq2 | p1: Bq0,Bq1 | p2: Bq2,Bq3 | p3: Aq1,Aq3.
// Last group: vmcnt(2) at p0, vmcnt(0) at p1, no staging.
// ---------------------------------------------------------------------------
#define BM 256
#define BN 256
#define BK 64
#define NT 43            // N_DIM/256
#define MT 16            // M_DIM/256
#define NWG (NT*MT)      // 688 = 8*86 -> bijective XCD swizzle

#define MFMA4(AV, R)                                                          \
    acc[(R)][0] = __builtin_amdgcn_mfma_f32_16x16x32_bf16((AV), b0, acc[(R)][0], 0,0,0); \
    acc[(R)][1] = __builtin_amdgcn_mfma_f32_16x16x32_bf16((AV), b1, acc[(R)][1], 0,0,0); \
    acc[(R)][2] = __builtin_amdgcn_mfma_f32_16x16x32_bf16((AV), b2, acc[(R)][2], 0,0,0); \
    acc[(R)][3] = __builtin_amdgcn_mfma_f32_16x16x32_bf16((AV), b3, acc[(R)][3], 0,0,0);

// One K-tile (4 ks-major phases).  ar0/ar1, br0/br1 = this buffer's per-lane
// ds_read bases for ks0/ks1 swizzled columns.  soff = staging buffer offset.
template<bool DO_STAGE>
__device__ __forceinline__ void kgroup(
        const __bf16* __restrict__ ar0, const __bf16* __restrict__ ar1,
        const __bf16* __restrict__ br0, const __bf16* __restrict__ br1,
        const __bf16* (&gsrc)[8], __bf16* lds, const int (&ldst)[8],
        const int soff, f32x4 (&acc)[8][4])
{
    bf16x8 a0, a1, a2, a3, b0, b1, b2, b3;

    // ---- p0 : ks0, mf0-3 (needs fresh Aq0/Aq2 + all B quarters) ----
    asm volatile("s_waitcnt vmcnt(2)" ::: "memory");
    BAR();
    a0 = *(const bf16x8*)(ar0 + 0*1024);
    a1 = *(const bf16x8*)(ar0 + 1*1024);
    a2 = *(const bf16x8*)(ar0 + 2*1024);
    a3 = *(const bf16x8*)(ar0 + 3*1024);
    b0 = *(const bf16x8*)(br0 + 0*1024);
    b1 = *(const bf16x8*)(br0 + 1*1024);
    b2 = *(const bf16x8*)(br0 + 2*1024);
    b3 = *(const bf16x8*)(br0 + 3*1024);
    if constexpr (DO_STAGE) {
        async16(gsrc[0], lds + ldst[0] + soff);
        async16(gsrc[1], lds + ldst[1] + soff);
    }
    BAR();
    __builtin_amdgcn_s_setprio(1);
    MFMA4(a0, 0) MFMA4(a1, 1) MFMA4(a2, 2) MFMA4(a3, 3)
    __builtin_amdgcn_s_setprio(0);

    // ---- p1 : ks0, mf4-7 (needs fresh Aq1/Aq3) ----
    if constexpr (DO_STAGE) { asm volatile("s_waitcnt vmcnt(2)" ::: "memory"); }
    else                    { asm volatile("s_waitcnt vmcnt(0)" ::: "memory"); }
    BAR();
    a0 = *(const bf16x8*)(ar0 + 4*1024);
    a1 = *(const bf16x8*)(ar0 + 5*1024);
    a2 = *(const bf16x8*)(ar0 + 6*1024);
    a3 = *(const bf16x8*)(ar0 + 7*1024);
    if constexpr (DO_STAGE) {
        async16(gsrc[2], lds + ldst[2] + soff);
        async16(gsrc[3], lds + ldst[3] + soff);
    }
    BAR();
    __builtin_amdgcn_s_setprio(1);
    MFMA4(a0, 4) MFMA4(a1, 5) MFMA4(a2, 6) MFMA4(a3, 7)
    __builtin_amdgcn_s_setprio(0);

    // ---- p2 : ks1, mf0-3 (data already waited at p0) ----
    BAR();
    a0 = *(const bf16x8*)(ar1 + 0*1024);
    a1 = *(const bf16x8*)(ar1 + 1*1024);
    a2 = *(const bf16x8*)(ar1 + 2*1024);
    a3 = *(const bf16x8*)(ar1 + 3*1024);
    b0 = *(const bf16x8*)(br1 + 0*1024);
    b1 = *(const bf16x8*)(br1 + 1*1024);
    b2 = *(const bf16x8*)(br1 + 2*1024);
    b3 = *(const bf16x8*)(br1 + 3*1024);
    if constexpr (DO_STAGE) {
        async16(gsrc[4], lds + ldst[4] + soff);
        async16(gsrc[5], lds + ldst[5] + soff);
    }
    BAR();
    __builtin_amdgcn_s_setprio(1);
    MFMA4(a0, 0) MFMA4(a1, 1) MFMA4(a2, 2) MFMA4(a3, 3)
    __builtin_amdgcn_s_setprio(0);

    // ---- p3 : ks1, mf4-7 ----
    BAR();
    a0 = *(const bf16x8*)(ar1 + 4*1024);
    a1 = *(const bf16x8*)(ar1 + 5*1024);
    a2 = *(const bf16x8*)(ar1 + 6*1024);
    a3 = *(const bf16x8*)(ar1 + 7*1024);
    if constexpr (DO_STAGE) {
        async16(gsrc[6], lds + ldst[6] + soff);
        async16(gsrc[7], lds + ldst[7] + soff);
    }
    BAR();
    __builtin_amdgcn_s_setprio(1);
    MFMA4(a0, 4) MFMA4(a1, 5) MFMA4(a2, 6) MFMA4(a3, 7)
    __builtin_amdgcn_s_setprio(0);

    if constexpr (DO_STAGE) {
#pragma unroll
        for (int j = 0; j < 8; ++j) gsrc[j] += BK;
    }
}

__global__ __launch_bounds__(512, 2) void gemm_kernel(
        const __bf16* __restrict__ A,    // M x K row-major (bf16 x)
        const __bf16* __restrict__ Bt,   // N x K row-major (dequant W^T)
        const float* __restrict__ bias,  // N
        float* __restrict__ C) {         // M x N row-major
    __shared__ __align__(16) __bf16 lds[65536];   // 128 KiB

    const int tid  = threadIdx.x;
    const int wave = tid >> 6;
    const int lane = tid & 63;
    const int wm   = wave >> 2;      // 0..1
    const int wn   = wave & 3;       // 0..3
    const int quad = lane >> 4;      // 0..3
    const int l16  = lane & 15;

    // bijective XCD swizzle (688 % 8 == 0), m inner for B-panel L2 reuse
    const int bid = blockIdx.x;
    const int swz = (bid & 7) * (NWG / 8) + (bid >> 3);
    const int n_t = swz >> 4;        // 0..42
    const int m_t = swz & 15;        // 0..15
    const int m0 = m_t << 8;
    const int n0 = n_t << 8;

    f32x4 acc[8][4] = {};

    // ---- staging source (pre-swizzled global addresses, rule 21) ----
    const int srow = tid >> 3;                       // 0..63 row within quarter
    const int scol = ((tid & 7) ^ (srow & 7)) << 3;  // swizzled k-chunk * 8

    // issue order: Aq0, Aq2, Bq0, Bq1, Bq2, Bq3, Aq1, Aq3
    const __bf16* gsrc[8];
    gsrc[0] = A  + (size_t)(m0 +   0 + srow) * K_DIM + scol;
    gsrc[1] = A  + (size_t)(m0 + 128 + srow) * K_DIM + scol;
    gsrc[2] = Bt + (size_t)(n0 +   0 + srow) * K_DIM + scol;
    gsrc[3] = Bt + (size_t)(n0 +  64 + srow) * K_DIM + scol;
    gsrc[4] = Bt + (size_t)(n0 + 128 + srow) * K_DIM + scol;
    gsrc[5] = Bt + (size_t)(n0 + 192 + srow) * K_DIM + scol;
    gsrc[6] = A  + (size_t)(m0 +  64 + srow) * K_DIM + scol;
    gsrc[7] = A  + (size_t)(m0 + 192 + srow) * K_DIM + scol;

    // wave-uniform LDS dest (elements): quarter base + wave*512 (HW adds lane*16B)
    const int wq = wave << 9;
    const int ldst[8] = {
        0*4096 + wq,          2*4096 + wq,
        32768 + 0*4096 + wq,  32768 + 1*4096 + wq,
        32768 + 2*4096 + wq,  32768 + 3*4096 + wq,
        1*4096 + wq,          3*4096 + wq
    };

    // prologue: tile 0 -> buf0 (same issue order as steady state)
#pragma unroll
    for (int j = 0; j < 8; ++j) async16(gsrc[j], lds + ldst[j]);
#pragma unroll
    for (int j = 0; j < 8; ++j) gsrc[j] += BK;

    // ---- compute-side ds_read bases (swizzled cols; row&7 == l16&7) ----
    const int h3  = l16 & 7;
    const int cc0 = (quad ^ h3) << 3;          // ks0 col (elements)
    const int cc1 = ((quad ^ h3) ^ 4) << 3;    // ks1 col = cc0 XOR 32 elems
    const int arow = (wm << 7) + l16;          // + mf*16 via imm offset
    const int brow = (wn << 6) + l16;          // + nf*16 via imm offset

    const __bf16* a00 = lds + arow * 64 + cc0;          // buf0 A ks0
    const __bf16* a01 = lds + arow * 64 + cc1;          // buf0 A ks1
    const __bf16* b00 = lds + 32768 + brow * 64 + cc0;  // buf0 B ks0
    const __bf16* b01 = lds + 32768 + brow * 64 + cc1;  // buf0 B ks1

    // 64 K-tiles: groups alternate buf0/buf1; group g stages tile g+1
    // (2 issues per phase) into the buffer vacated at end of group g-1.
#pragma unroll 1
    for (int gg = 0; gg < 31; ++gg) {
        kgroup<true>(a00,         a01,         b00,         b01,
                     gsrc, lds, ldst, 16384, acc);
        kgroup<true>(a00 + 16384, a01 + 16384, b00 + 16384, b01 + 16384,
                     gsrc, lds, ldst, 0,     acc);
    }
    kgroup<true >(a00,         a01,         b00,         b01,
                  gsrc, lds, ldst, 16384, acc);   // g=62 stages tile 63
    kgroup<false>(a00 + 16384, a01 + 16384, b00 + 16384, b01 + 16384,
                  gsrc, lds, ldst, 0,     acc);   // g=63, drain

    // ---- epilogue: C[m][n] = acc + bias[n]; C/D: col=l16, row=quad*4+r ----
#pragma unroll
    for (int nf = 0; nf < 4; ++nf) {
        const int n = n0 + (wn << 6) + (nf << 4) + l16;
        const float bv = bias[n];
#pragma unroll
        for (int mf = 0; mf < 8; ++mf) {
            const int mrow = m0 + (wm << 7) + (mf << 4) + (quad << 2);
            float* cp = C + (size_t)mrow * N_DIM + n;
#pragma unroll
            for (int r = 0; r < 4; ++r)
                cp[(size_t)r * N_DIM] = acc[mf][nf][r] + bv;
        }
    }
}

// ---------------------------------------------------------------------------
extern "C" void kernel_launch(void* const* d_in, const int* in_sizes, int n_in,
                              void* d_out, int out_size, void* d_ws, size_t ws_size,
                              hipStream_t stream) {
    const float*    x      = (const float*)d_in[0];
    const uint32_t* qw     = (const uint32_t*)d_in[1];
    const float*    scales = (const float*)d_in[2];
    const float*    zeros  = (const float*)d_in[3];
    const float*    bias   = (const float*)d_in[4];
    float*          out    = (float*)d_out;

    // workspace layout: Wt (N*K bf16 = 90,177,536 B) | xb (M*K bf16 = 33,554,432 B)
    __bf16* Wt = (__bf16*)d_ws;
    __bf16* xb = (__bf16*)((char*)d_ws + (size_t)N_DIM * K_DIM * sizeof(__bf16));

    dim3 dq_grid(N_DIM / DQ_NN, QROWS / DQ_KK);   // 172 x 16
    dequant_kernel<<<dq_grid, 256, 0, stream>>>(qw, scales, zeros, Wt);
    xconv_kernel<<<(M_DIM * K_DIM) / (256 * 8), 256, 0, stream>>>(x, xb);

    gemm_kernel<<<NWG, 512, 0, stream>>>(xb, Wt, bias, out);
}

// Round 4
// 584.991 us; speedup vs baseline: 1.0548x; 1.0310x over previous
//
#include <hip/hip_runtime.h>
#include <hip/hip_bf16.h>
#include <cstdint>
#include <cstddef>

// Problem constants
#define K_DIM   4096          // INF
#define N_DIM   11008         // OUTF
#define M_DIM   4096          // 2*2048
#define GROUPS  32
#define QROWS   512           // INF*4/32

typedef __bf16 bf16x8 __attribute__((ext_vector_type(8)));
typedef float  f32x4  __attribute__((ext_vector_type(4)));

// ---------------------------------------------------------------------------
// async 16B global -> LDS (wave-uniform LDS base + lane*16 semantics)
// ---------------------------------------------------------------------------
__device__ __forceinline__ void async16(const void* g, void* lds) {
    __builtin_amdgcn_global_load_lds(
        (const __attribute__((address_space(1))) uint32_t*)g,
        (__attribute__((address_space(3))) uint32_t*)lds,
        16, 0, 0);
}

#define FENCE() asm volatile("" ::: "memory")
#define BAR()   do { FENCE(); __builtin_amdgcn_s_barrier(); FENCE(); } while (0)

// ---------------------------------------------------------------------------
// Kernel 1: dequantize packed 4-bit weights into B^T bf16 layout (N x K).
// (unchanged — revisit once GEMM no longer dominates)
// ---------------------------------------------------------------------------
#define DQ_NN   64
#define DQ_KK   32
#define DQ_ROW  264   // 256 k-elements + 8 pad (16B) -> 528B row stride
__global__ __launch_bounds__(256) void dequant_kernel(
        const uint32_t* __restrict__ qw,
        const float* __restrict__ scales,
        const float* __restrict__ zeros,
        __bf16* __restrict__ Wt) {
    __shared__ __align__(16) __bf16 T[DQ_NN * DQ_ROW];   // 33,792 B

    const int n0  = blockIdx.x * DQ_NN;
    const int kk0 = blockIdx.y * DQ_KK;
    const int tid = threadIdx.x;

#pragma unroll
    for (int it = 0; it < 8; ++it) {
        const int flat = it * 256 + tid;
        const int kk_l = flat >> 6;          // 0..31
        const int n_l  = flat & 63;          // 0..63
        const int kk   = kk0 + kk_l;
        const int n    = n0 + n_l;
        const uint32_t q = qw[(size_t)kk * N_DIM + n];
        const int g = kk >> 4;               // k-group = (kk*8)/128
        const float s = scales[(size_t)n * GROUPS + g];
        const float z = zeros[(size_t)n * GROUPS + g];
        bf16x8 w;
#pragma unroll
        for (int j = 0; j < 8; ++j) {
            float v = (float)((q >> (4 * j)) & 0xF) * s - z;
            w[j] = (__bf16)v;
        }
        *(bf16x8*)(&T[n_l * DQ_ROW + kk_l * 8]) = w;
    }
    __syncthreads();

#pragma unroll
    for (int it = 0; it < 8; ++it) {
        const int flat = it * 256 + tid;
        const int n_l    = flat >> 5;        // 0..63
        const int kchunk = flat & 31;        // 0..31 (8 elems each)
        bf16x8 v = *(const bf16x8*)(&T[n_l * DQ_ROW + kchunk * 8]);
        *(bf16x8*)(Wt + (size_t)(n0 + n_l) * K_DIM + (size_t)kk0 * 8 + kchunk * 8) = v;
    }
}

// ---------------------------------------------------------------------------
// Kernel 2: x fp32 -> bf16 (RNE), 8 elements per thread (unchanged)
// ---------------------------------------------------------------------------
__global__ __launch_bounds__(256) void xconv_kernel(
        const float* __restrict__ x, __bf16* __restrict__ xb) {
    const size_t i = ((size_t)blockIdx.x * 256 + threadIdx.x) * 8;
    const float4* p = (const float4*)(x + i);
    float4 a = p[0];
    float4 b = p[1];
    bf16x8 o;
    o[0] = (__bf16)a.x; o[1] = (__bf16)a.y; o[2] = (__bf16)a.z; o[3] = (__bf16)a.w;
    o[4] = (__bf16)b.x; o[5] = (__bf16)b.y; o[6] = (__bf16)b.z; o[7] = (__bf16)b.w;
    *(bf16x8*)(xb + i) = o;
}

// ---------------------------------------------------------------------------
// Kernel 3: bf16 GEMM, C = A(M x K) * Bt(N x K)^T + bias, fp32 out.
//
// 256x256 tile, BK=64, 512 threads = 8 waves (2M x 4N), per-wave 128x64
// output = acc[8][4] f32x4.  XOR-8 LDS swizzle via pre-swizzled global
// source (rule 21).  XCD-bijective block swizzle.
//
// R3 change: ONE barrier per K-tile (was 8).  Correctness argument:
//  (i) stagings into buffer Y (tile g+1, issued at g's p0/p1) follow all
//      reads of Y (tile g-1 data): each wave's last Y-read is lgkm(0)-waited
//      before M(p3,g-1), which precedes its arrival at g's p0 barrier;
//      barrier => all waves arrived => safe.
//  (ii) reads of Y (at g+1's p0..p3) follow all stagings into Y: per-wave
//      vmcnt(0) BEFORE the p0 barrier certifies own 8 stagings (aged
//      2.5-3.5 phases ~ 2000cyc >> HBM latency -> free drain); barrier
//      publishes cross-wave.
// All 8 staging issues moved to p0(4)+p1(4) to maximize age at the wait.
// No per-phase barriers -> waves slip across phases -> LDS reads and MFMA
// issue overlap cross-wave (m114 mechanism); setprio arbitrates.
// ---------------------------------------------------------------------------
#define BM 256
#define BN 256
#define BK 64
#define NT 43            // N_DIM/256
#define MT 16            // M_DIM/256
#define NWG (NT*MT)      // 688 = 8*86 -> bijective XCD swizzle

#define MFMA4(AV, R)                                                          \
    acc[(R)][0] = __builtin_amdgcn_mfma_f32_16x16x32_bf16((AV), b0, acc[(R)][0], 0,0,0); \
    acc[(R)][1] = __builtin_amdgcn_mfma_f32_16x16x32_bf16((AV), b1, acc[(R)][1], 0,0,0); \
    acc[(R)][2] = __builtin_amdgcn_mfma_f32_16x16x32_bf16((AV), b2, acc[(R)][2], 0,0,0); \
    acc[(R)][3] = __builtin_amdgcn_mfma_f32_16x16x32_bf16((AV), b3, acc[(R)][3], 0,0,0);

#define WAIT_LGKM0()                                                          \
    do { asm volatile("s_waitcnt lgkmcnt(0)" ::: "memory");                   \
         __builtin_amdgcn_sched_barrier(0); } while (0)

// One K-tile (4 ks-major phases, ONE barrier).  ar0/ar1, br0/br1 = this
// buffer's per-lane ds_read bases for ks0/ks1.  soff = staging buf offset.
template<bool DO_STAGE>
__device__ __forceinline__ void kgroup(
        const __bf16* __restrict__ ar0, const __bf16* __restrict__ ar1,
        const __bf16* __restrict__ br0, const __bf16* __restrict__ br1,
        const __bf16* (&gsrc)[8], __bf16* lds, const int (&ldst)[8],
        const int soff, f32x4 (&acc)[8][4])
{
    bf16x8 a0, a1, a2, a3, b0, b1, b2, b3;

    // ---- p0 : ks0, mf0-3 ----
    // Drain this tile's 8 stagings (issued 2.5-3.5 phases ago -> free),
    // then the tile's single barrier publishes them cross-wave.
    asm volatile("s_waitcnt vmcnt(0)" ::: "memory");
    BAR();
    if constexpr (DO_STAGE) {
        async16(gsrc[0], lds + ldst[0] + soff);
        async16(gsrc[1], lds + ldst[1] + soff);
        async16(gsrc[2], lds + ldst[2] + soff);
        async16(gsrc[3], lds + ldst[3] + soff);
    }
    a0 = *(const bf16x8*)(ar0 + 0*1024);
    a1 = *(const bf16x8*)(ar0 + 1*1024);
    a2 = *(const bf16x8*)(ar0 + 2*1024);
    a3 = *(const bf16x8*)(ar0 + 3*1024);
    b0 = *(const bf16x8*)(br0 + 0*1024);
    b1 = *(const bf16x8*)(br0 + 1*1024);
    b2 = *(const bf16x8*)(br0 + 2*1024);
    b3 = *(const bf16x8*)(br0 + 3*1024);
    WAIT_LGKM0();
    __builtin_amdgcn_s_setprio(1);
    MFMA4(a0, 0) MFMA4(a1, 1) MFMA4(a2, 2) MFMA4(a3, 3)
    __builtin_amdgcn_s_setprio(0);

    // ---- p1 : ks0, mf4-7 ----
    if constexpr (DO_STAGE) {
        async16(gsrc[4], lds + ldst[4] + soff);
        async16(gsrc[5], lds + ldst[5] + soff);
        async16(gsrc[6], lds + ldst[6] + soff);
        async16(gsrc[7], lds + ldst[7] + soff);
    }
    a0 = *(const bf16x8*)(ar0 + 4*1024);
    a1 = *(const bf16x8*)(ar0 + 5*1024);
    a2 = *(const bf16x8*)(ar0 + 6*1024);
    a3 = *(const bf16x8*)(ar0 + 7*1024);
    WAIT_LGKM0();
    __builtin_amdgcn_s_setprio(1);
    MFMA4(a0, 4) MFMA4(a1, 5) MFMA4(a2, 6) MFMA4(a3, 7)
    __builtin_amdgcn_s_setprio(0);

    // ---- p2 : ks1, mf0-3 ----
    a0 = *(const bf16x8*)(ar1 + 0*1024);
    a1 = *(const bf16x8*)(ar1 + 1*1024);
    a2 = *(const bf16x8*)(ar1 + 2*1024);
    a3 = *(const bf16x8*)(ar1 + 3*1024);
    b0 = *(const bf16x8*)(br1 + 0*1024);
    b1 = *(const bf16x8*)(br1 + 1*1024);
    b2 = *(const bf16x8*)(br1 + 2*1024);
    b3 = *(const bf16x8*)(br1 + 3*1024);
    WAIT_LGKM0();
    __builtin_amdgcn_s_setprio(1);
    MFMA4(a0, 0) MFMA4(a1, 1) MFMA4(a2, 2) MFMA4(a3, 3)
    __builtin_amdgcn_s_setprio(0);

    // ---- p3 : ks1, mf4-7 ----
    a0 = *(const bf16x8*)(ar1 + 4*1024);
    a1 = *(const bf16x8*)(ar1 + 5*1024);
    a2 = *(const bf16x8*)(ar1 + 6*1024);
    a3 = *(const bf16x8*)(ar1 + 7*1024);
    WAIT_LGKM0();
    __builtin_amdgcn_s_setprio(1);
    MFMA4(a0, 4) MFMA4(a1, 5) MFMA4(a2, 6) MFMA4(a3, 7)
    __builtin_amdgcn_s_setprio(0);

    if constexpr (DO_STAGE) {
#pragma unroll
        for (int j = 0; j < 8; ++j) gsrc[j] += BK;
    }
}

__global__ __launch_bounds__(512, 2) void gemm_kernel(
        const __bf16* __restrict__ A,    // M x K row-major (bf16 x)
        const __bf16* __restrict__ Bt,   // N x K row-major (dequant W^T)
        const float* __restrict__ bias,  // N
        float* __restrict__ C) {         // M x N row-major
    __shared__ __align__(16) __bf16 lds[65536];   // 128 KiB

    const int tid  = threadIdx.x;
    const int wave = tid >> 6;
    const int lane = tid & 63;
    const int wm   = wave >> 2;      // 0..1
    const int wn   = wave & 3;       // 0..3
    const int quad = lane >> 4;      // 0..3
    const int l16  = lane & 15;

    // bijective XCD swizzle (688 % 8 == 0), m inner for B-panel L2 reuse
    const int bid = blockIdx.x;
    const int swz = (bid & 7) * (NWG / 8) + (bid >> 3);
    const int n_t = swz >> 4;        // 0..42
    const int m_t = swz & 15;        // 0..15
    const int m0 = m_t << 8;
    const int n0 = n_t << 8;

    f32x4 acc[8][4] = {};

    // ---- staging source (pre-swizzled global addresses, rule 21) ----
    const int srow = tid >> 3;                       // 0..63 row within quarter
    const int scol = ((tid & 7) ^ (srow & 7)) << 3;  // swizzled k-chunk * 8

    // issue order: p0: Aq0, Aq2, Bq0, Bq1 | p1: Bq2, Bq3, Aq1, Aq3
    const __bf16* gsrc[8];
    gsrc[0] = A  + (size_t)(m0 +   0 + srow) * K_DIM + scol;
    gsrc[1] = A  + (size_t)(m0 + 128 + srow) * K_DIM + scol;
    gsrc[2] = Bt + (size_t)(n0 +   0 + srow) * K_DIM + scol;
    gsrc[3] = Bt + (size_t)(n0 +  64 + srow) * K_DIM + scol;
    gsrc[4] = Bt + (size_t)(n0 + 128 + srow) * K_DIM + scol;
    gsrc[5] = Bt + (size_t)(n0 + 192 + srow) * K_DIM + scol;
    gsrc[6] = A  + (size_t)(m0 +  64 + srow) * K_DIM + scol;
    gsrc[7] = A  + (size_t)(m0 + 192 + srow) * K_DIM + scol;

    // wave-uniform LDS dest (elements): quarter base + wave*512 (HW adds lane*16B)
    const int wq = wave << 9;
    const int ldst[8] = {
        0*4096 + wq,          2*4096 + wq,
        32768 + 0*4096 + wq,  32768 + 1*4096 + wq,
        32768 + 2*4096 + wq,  32768 + 3*4096 + wq,
        1*4096 + wq,          3*4096 + wq
    };

    // prologue: tile 0 -> buf0 (drained by the loop's first vmcnt(0)+BAR)
#pragma unroll
    for (int j = 0; j < 8; ++j) async16(gsrc[j], lds + ldst[j]);
#pragma unroll
    for (int j = 0; j < 8; ++j) gsrc[j] += BK;

    // ---- compute-side ds_read bases (swizzled cols; row&7 == l16&7) ----
    const int h3  = l16 & 7;
    const int cc0 = (quad ^ h3) << 3;          // ks0 col (elements)
    const int cc1 = ((quad ^ h3) ^ 4) << 3;    // ks1 col = cc0 XOR 32 elems
    const int arow = (wm << 7) + l16;          // + mf*16 via imm offset
    const int brow = (wn << 6) + l16;          // + nf*16 via imm offset

    const __bf16* a00 = lds + arow * 64 + cc0;          // buf0 A ks0
    const __bf16* a01 = lds + arow * 64 + cc1;          // buf0 A ks1
    const __bf16* b00 = lds + 32768 + brow * 64 + cc0;  // buf0 B ks0
    const __bf16* b01 = lds + 32768 + brow * 64 + cc1;  // buf0 B ks1

    // 64 K-tiles: groups alternate buf0/buf1; group g stages tile g+1
    // (4 issues at p0, 4 at p1) into the buffer vacated at end of g-1.
#pragma unroll 1
    for (int gg = 0; gg < 31; ++gg) {
        kgroup<true>(a00,         a01,         b00,         b01,
                     gsrc, lds, ldst, 16384, acc);
        kgroup<true>(a00 + 16384, a01 + 16384, b00 + 16384, b01 + 16384,
                     gsrc, lds, ldst, 0,     acc);
    }
    kgroup<true >(a00,         a01,         b00,         b01,
                  gsrc, lds, ldst, 16384, acc);   // g=62 stages tile 63
    kgroup<false>(a00 + 16384, a01 + 16384, b00 + 16384, b01 + 16384,
                  gsrc, lds, ldst, 0,     acc);   // g=63, drain only

    // ---- epilogue: C[m][n] = acc + bias[n]; C/D: col=l16, row=quad*4+r ----
#pragma unroll
    for (int nf = 0; nf < 4; ++nf) {
        const int n = n0 + (wn << 6) + (nf << 4) + l16;
        const float bv = bias[n];
#pragma unroll
        for (int mf = 0; mf < 8; ++mf) {
            const int mrow = m0 + (wm << 7) + (mf << 4) + (quad << 2);
            float* cp = C + (size_t)mrow * N_DIM + n;
#pragma unroll
            for (int r = 0; r < 4; ++r)
                cp[(size_t)r * N_DIM] = acc[mf][nf][r] + bv;
        }
    }
}

// ---------------------------------------------------------------------------
extern "C" void kernel_launch(void* const* d_in, const int* in_sizes, int n_in,
                              void* d_out, int out_size, void* d_ws, size_t ws_size,
                              hipStream_t stream) {
    const float*    x      = (const float*)d_in[0];
    const uint32_t* qw     = (const uint32_t*)d_in[1];
    const float*    scales = (const float*)d_in[2];
    const float*    zeros  = (const float*)d_in[3];
    const float*    bias   = (const float*)d_in[4];
    float*          out    = (float*)d_out;

    // workspace layout: Wt (N*K bf16 = 90,177,536 B) | xb (M*K bf16 = 33,554,432 B)
    __bf16* Wt = (__bf16*)d_ws;
    __bf16* xb = (__bf16*)((char*)d_ws + (size_t)N_DIM * K_DIM * sizeof(__bf16));

    dim3 dq_grid(N_DIM / DQ_NN, QROWS / DQ_KK);   // 172 x 16
    dequant_kernel<<<dq_grid, 256, 0, stream>>>(qw, scales, zeros, Wt);
    xconv_kernel<<<(M_DIM * K_DIM) / (256 * 8), 256, 0, stream>>>(x, xb);

    gemm_kernel<<<NWG, 512, 0, stream>>>(xb, Wt, bias, out);
}